// Round 5
// baseline (180.849 us; speedup 1.0000x reference)
//
#include <hip/hip_runtime.h>
#include <math.h>

#define BATCH   32
#define N_BEADS 16384
#define BEAD_SIZE 16
#define N_ATOMS 100000
#define INV_SQRT2 0.70710678118654752440f
#define SCAN_BLK 256

// ======================= build chain =======================
// counts + per-m packed records in one pass.
// rec1[m] = {slot(bits), w0, w1, w2}        (for rot_kernel)
// rec2[m] = {h(bits), 2*cos*sin, 2*sin^2}   (for sum_kernel, Rodrigues)
__global__ void __launch_bounds__(256)
countrec_kernel(const int* __restrict__ atom_idx,
                const int* __restrict__ slot_idx,
                const float* __restrict__ ang,
                const float* __restrict__ W,
                int* __restrict__ counts,
                float4* __restrict__ rec1,
                float4* __restrict__ rec2,
                int M)
{
    int m = blockIdx.x * blockDim.x + threadIdx.x;
    if (m >= M) return;
    atomicAdd(&counts[atom_idx[m]], 1);
    int slot = slot_idx[m];
    int h = slot >> 4, l = slot & 15;
    float w0 = W[(0 * N_BEADS + h) * BEAD_SIZE + l];
    float w1 = W[(1 * N_BEADS + h) * BEAD_SIZE + l];
    float w2 = W[(2 * N_BEADS + h) * BEAD_SIZE + l];
    float sa, ca;
    __sincosf(ang[m], &sa, &ca);
    rec1[m] = make_float4(__int_as_float(slot), w0, w1, w2);
    rec2[m] = make_float4(__int_as_float(h), 2.f * ca * sa, 2.f * sa * sa, 0.f);
}

__global__ void __launch_bounds__(SCAN_BLK)
scan1_kernel(const int* __restrict__ counts, int* __restrict__ off,
             int* __restrict__ bsum, int n)
{
    __shared__ int s[SCAN_BLK];
    int i = blockIdx.x * SCAN_BLK + threadIdx.x;
    int c = (i < n) ? counts[i] : 0;
    s[threadIdx.x] = c;
    __syncthreads();
    int v = c;
    for (int d = 1; d < SCAN_BLK; d <<= 1) {
        int t = (threadIdx.x >= d) ? s[threadIdx.x - d] : 0;
        __syncthreads();
        v += t;
        s[threadIdx.x] = v;
        __syncthreads();
    }
    if (i < n) off[i] = v - c;
    if (threadIdx.x == SCAN_BLK - 1) bsum[blockIdx.x] = v;
}

__global__ void __launch_bounds__(512)
scan2_kernel(const int* __restrict__ bsum, int* __restrict__ bsum2, int nb)
{
    __shared__ int s[512];
    int i = threadIdx.x;
    int c = (i < nb) ? bsum[i] : 0;
    s[i] = c;
    __syncthreads();
    int v = c;
    for (int d = 1; d < 512; d <<= 1) {
        int t = (i >= d) ? s[i - d] : 0;
        __syncthreads();
        v += t;
        s[i] = v;
        __syncthreads();
    }
    if (i < nb) bsum2[i] = v - c;
}

// finalize offsets, zero fill-cursor, build per-atom record {cnt, off, scal}
__global__ void __launch_bounds__(256)
scan3_kernel(int* __restrict__ off, const int* __restrict__ bsum2,
             const int* __restrict__ counts, const float* __restrict__ scal,
             int* __restrict__ cursor2, float4* __restrict__ rec_a, int n)
{
    int i = blockIdx.x * blockDim.x + threadIdx.x;
    if (i >= n) return;
    int o = off[i] + bsum2[i / SCAN_BLK];
    off[i] = o;
    cursor2[i] = 0;
    rec_a[i] = make_float4(__int_as_float(counts[i]), __int_as_float(o),
                           scal[i], 0.f);
}

__global__ void __launch_bounds__(256)
fill_kernel(const int* __restrict__ atom_idx, const int* __restrict__ off,
            int* __restrict__ cursor2, int* __restrict__ csr_m, int M)
{
    int m = blockIdx.x * blockDim.x + threadIdx.x;
    if (m >= M) return;
    int a = atom_idx[m];
    int k = atomicAdd(&cursor2[a], 1);
    csr_m[off[a] + k] = m;
}

// ======================= pass 1: rot only =======================
// 2D grid (y = b) kills the integer divide; LDS-staged dwordx4 stores.
__global__ void __launch_bounds__(256)
rot_kernel(const float* __restrict__ p1, const float* __restrict__ p2,
           const float4* __restrict__ rec1, float* __restrict__ out_rot, int M)
{
    int b = blockIdx.y;
    int mbase = blockIdx.x * 256;
    int m = mbase + threadIdx.x;
    __shared__ float sbuf[768];

    float rx = 0.f, ry = 0.f, rz = 0.f;
    if (m < M) {
        float4 r = rec1[m];
        int slot = __float_as_int(r.x);
        int h = slot >> 4;
        const float* p1p = p1 + ((size_t)b * N_BEADS + h) * 3;
        const float* p2p = p2 + ((size_t)b * N_BEADS + h) * 3;
        float a1x = p1p[0], a1y = p1p[1], a1z = p1p[2];
        float a2x = p2p[0], a2y = p2p[1], a2z = p2p[2];
        float cxx = (a1y * a2z - a1z * a2y) * INV_SQRT2;
        float cyy = (a1z * a2x - a1x * a2z) * INV_SQRT2;
        float czz = (a1x * a2y - a1y * a2x) * INV_SQRT2;
        rx = r.y * a1x + r.z * a2x + r.w * cxx;
        ry = r.y * a1y + r.z * a2y + r.w * cyy;
        rz = r.y * a1z + r.z * a2z + r.w * czz;
        float inv = rsqrtf(rx * rx + ry * ry + rz * rz);
        rx *= inv; ry *= inv; rz *= inv;
    }
    sbuf[threadIdx.x * 3 + 0] = rx;
    sbuf[threadIdx.x * 3 + 1] = ry;
    sbuf[threadIdx.x * 3 + 2] = rz;
    __syncthreads();

    int nm = M - mbase; if (nm > 256) nm = 256;
    int nf = nm * 3;
    size_t base = ((size_t)b * M + mbase) * 3;
    if (((base * sizeof(float)) & 15) == 0) {
        int nf4 = nf >> 2;
        float4* dst = (float4*)(out_rot + base);
        if ((int)threadIdx.x < nf4)
            dst[threadIdx.x] = ((const float4*)sbuf)[threadIdx.x];
        int done = nf4 << 2;
        int r = nf - done;
        if ((int)threadIdx.x < r)
            out_rot[base + done + threadIdx.x] = sbuf[done + threadIdx.x];
    } else if (m < M) {
        out_rot[base + threadIdx.x * 3 + 0] = rx;
        out_rot[base + threadIdx.x * 3 + 1] = ry;
        out_rot[base + threadIdx.x * 3 + 2] = rz;
    }
}

// ======================= pass 2: CSR sum, recompute rotation =======================
// XCD x owns b = x, x+8, x+16, x+24 -> rot b-slice (1.67 MB) L2-resident.
// Rodrigues: v' = v + A*(r x v) + B*(r x (r x v)), A=2cs, B=2s^2.
__global__ void __launch_bounds__(256)
sum_kernel(const float4* __restrict__ rec_a,
           const int* __restrict__ csr_m,
           const float4* __restrict__ rec2,
           const float* __restrict__ rot,
           const float* __restrict__ p1,
           const float* __restrict__ P,
           float* __restrict__ out_atoms,
           int M, int abps)
{
    int beta = blockIdx.x;
    int xcd  = beta & 7;
    int j    = beta >> 3;
    int round = j / abps;                 // 0..3
    int ablk  = j - round * abps;
    int b = xcd + 8 * round;
    int abase = ablk * 256;
    int a = abase + threadIdx.x;

    float ax = 0.f, ay = 0.f, az = 0.f;
    if (a < N_ATOMS) {
        float4 ra = rec_a[a];
        int cnt = __float_as_int(ra.x);
        int o   = __float_as_int(ra.y);
        float s = ra.z;
        const float* rb  = rot + (size_t)b * M * 3;
        const float* p1b = p1  + (size_t)b * N_BEADS * 3;
        const float* Pb  = P   + (size_t)b * N_BEADS * 3;
        for (int k = 0; k < cnt; ++k) {
            int m = csr_m[o + k];
            float4 r2 = rec2[m];
            int h = __float_as_int(r2.x);
            float A = r2.y, Bc = r2.z;
            const float* ro = rb + (size_t)m * 3;
            float rx = ro[0], ry = ro[1], rz = ro[2];
            const float* vp = p1b + (size_t)h * 3;
            float vx = vp[0], vy = vp[1], vz = vp[2];
            float ux = ry * vz - rz * vy;
            float uy = rz * vx - rx * vz;
            float uz = rx * vy - ry * vx;
            float wx = ry * uz - rz * uy;
            float wy = rz * ux - rx * uz;
            float wz = rx * uy - ry * ux;
            float vrx = vx + A * ux + Bc * wx;
            float vry = vy + A * uy + Bc * wy;
            float vrz = vz + A * uz + Bc * wz;
            const float* Pp = Pb + (size_t)h * 3;
            ax += s * vrx + Pp[0];
            ay += s * vry + Pp[1];
            az += s * vrz + Pp[2];
        }
    }
    __shared__ float sbuf[768];
    sbuf[threadIdx.x * 3 + 0] = ax;
    sbuf[threadIdx.x * 3 + 1] = ay;
    sbuf[threadIdx.x * 3 + 2] = az;
    __syncthreads();

    int na = N_ATOMS - abase; if (na > 256) na = 256;
    int nf = na * 3;
    size_t base = ((size_t)b * N_ATOMS + abase) * 3;   // always 16B-aligned here
    int nf4 = nf >> 2;
    float4* dst = (float4*)(out_atoms + base);
    if ((int)threadIdx.x < nf4)
        dst[threadIdx.x] = ((const float4*)sbuf)[threadIdx.x];
    int done = nf4 << 2;
    int r = nf - done;
    if ((int)threadIdx.x < r)
        out_atoms[base + done + threadIdx.x] = sbuf[done + threadIdx.x];
}

// ======================= fallback: atomic scatter (ws-independent) =======================
__global__ void __launch_bounds__(256)
backmap_fallback(const float* __restrict__ P, const float* __restrict__ p1,
                 const float* __restrict__ p2, const float* __restrict__ W,
                 const float* __restrict__ ang, const float* __restrict__ scal,
                 const int* __restrict__ slot_idx, const int* __restrict__ atom_idx,
                 const int* __restrict__ bead_idx,
                 float* __restrict__ out_atoms, float* __restrict__ out_rot, int M)
{
    int t = blockIdx.x * blockDim.x + threadIdx.x;
    if (t >= BATCH * M) return;
    int b = t / M; int m = t - b * M;
    int slot = slot_idx[m]; int h = slot >> 4; int l = slot & 15;
    int bead = bead_idx[m]; int atom = atom_idx[m];
    const float* p1p = p1 + ((size_t)b * N_BEADS + h) * 3;
    const float* p2p = p2 + ((size_t)b * N_BEADS + h) * 3;
    float a1x = p1p[0], a1y = p1p[1], a1z = p1p[2];
    float a2x = p2p[0], a2y = p2p[1], a2z = p2p[2];
    float cx = (a1y * a2z - a1z * a2y) * INV_SQRT2;
    float cy = (a1z * a2x - a1x * a2z) * INV_SQRT2;
    float cz = (a1x * a2y - a1y * a2x) * INV_SQRT2;
    float w0 = W[(0 * N_BEADS + h) * BEAD_SIZE + l];
    float w1 = W[(1 * N_BEADS + h) * BEAD_SIZE + l];
    float w2 = W[(2 * N_BEADS + h) * BEAD_SIZE + l];
    float rx = w0 * a1x + w1 * a2x + w2 * cx;
    float ry = w0 * a1y + w1 * a2y + w2 * cy;
    float rz = w0 * a1z + w1 * a2z + w2 * cz;
    float inv = rsqrtf(rx * rx + ry * ry + rz * rz);
    rx *= inv; ry *= inv; rz *= inv;
    float* ro = out_rot + (size_t)t * 3;
    ro[0] = rx; ro[1] = ry; ro[2] = rz;
    float sa, ca; __sincosf(ang[m], &sa, &ca);
    float qw = ca, qx = sa * rx, qy = sa * ry, qz = sa * rz;
    const float* vp = p1 + ((size_t)b * N_BEADS + bead) * 3;
    float vx = vp[0], vy = vp[1], vz = vp[2];
    float tw = -qx * vx - qy * vy - qz * vz;
    float tx =  qw * vx + qy * vz - qz * vy;
    float ty =  qw * vy + qz * vx - qx * vz;
    float tz =  qw * vz + qx * vy - qy * vx;
    float vrx = -tw * qx + tx * qw - ty * qz + tz * qy;
    float vry = -tw * qy + ty * qw - tz * qx + tx * qz;
    float vrz = -tw * qz + tz * qw - tx * qy + ty * qx;
    float s = scal[atom];
    const float* Pp = P + ((size_t)b * N_BEADS + bead) * 3;
    float* op = out_atoms + ((size_t)b * N_ATOMS + atom) * 3;
    atomicAdd(op + 0, s * vrx + Pp[0]);
    atomicAdd(op + 1, s * vry + Pp[1]);
    atomicAdd(op + 2, s * vrz + Pp[2]);
}

extern "C" void kernel_launch(void* const* d_in, const int* in_sizes, int n_in,
                              void* d_out, int out_size, void* d_ws, size_t ws_size,
                              hipStream_t stream) {
    const float* P    = (const float*)d_in[0];
    const float* p1   = (const float*)d_in[1];
    const float* p2   = (const float*)d_in[2];
    const float* W    = (const float*)d_in[3];
    const float* ang  = (const float*)d_in[4];
    const float* scal = (const float*)d_in[5];
    const int* slot_idx = (const int*)d_in[6];
    const int* atom_idx = (const int*)d_in[7];
    const int* bead_idx = (const int*)d_in[8];

    int M = in_sizes[6];
    float* out_atoms = (float*)d_out;
    float* out_rot   = out_atoms + (size_t)BATCH * N_ATOMS * 3;

    int nblk = (N_ATOMS + SCAN_BLK - 1) / SCAN_BLK;   // 391

    // ws: counts|off|cursor2 (ints) | bsum|bsum2 (512 ints each)
    //     rec1[M] | rec2[M] | rec_a[N_ATOMS] (float4) | csr_m[M] (int)
    size_t need = (size_t)N_ATOMS * 4 * 3 + 512 * 4 * 2
                + (size_t)M * 16 * 2 + (size_t)N_ATOMS * 16 + (size_t)M * 4;

    if (ws_size >= need) {
        int* counts  = (int*)d_ws;
        int* off     = counts + N_ATOMS;
        int* cursor2 = off + N_ATOMS;
        int* bsum    = cursor2 + N_ATOMS;
        int* bsum2   = bsum + 512;
        float4* rec1 = (float4*)(bsum2 + 512);        // int-prefix = 1,204,096 B, 16B-aligned
        float4* rec2 = rec1 + M;
        float4* rec_a = rec2 + M;
        int* csr_m   = (int*)(rec_a + N_ATOMS);

        hipMemsetAsync(counts, 0, (size_t)N_ATOMS * sizeof(int), stream);
        countrec_kernel<<<(M + 255) / 256, 256, 0, stream>>>(
            atom_idx, slot_idx, ang, W, counts, rec1, rec2, M);
        scan1_kernel<<<nblk, SCAN_BLK, 0, stream>>>(counts, off, bsum, N_ATOMS);
        scan2_kernel<<<1, 512, 0, stream>>>(bsum, bsum2, nblk);
        scan3_kernel<<<nblk, 256, 0, stream>>>(off, bsum2, counts, scal,
                                               cursor2, rec_a, N_ATOMS);
        fill_kernel<<<(M + 255) / 256, 256, 0, stream>>>(
            atom_idx, off, cursor2, csr_m, M);

        dim3 g1((M + 255) / 256, BATCH);
        rot_kernel<<<g1, 256, 0, stream>>>(p1, p2, rec1, out_rot, M);

        int abps = (N_ATOMS + 255) / 256;             // 391
        sum_kernel<<<abps * BATCH, 256, 0, stream>>>(
            rec_a, csr_m, rec2, out_rot, p1, P, out_atoms, M, abps);
        return;
    }

    // fallback: atomic scatter
    hipMemsetAsync(out_atoms, 0, (size_t)BATCH * N_ATOMS * 3 * sizeof(float), stream);
    int total = BATCH * M;
    backmap_fallback<<<(total + 255) / 256, 256, 0, stream>>>(
        P, p1, p2, W, ang, scal, slot_idx, atom_idx, bead_idx,
        out_atoms, out_rot, M);
}

// Round 6
// 136.997 us; speedup vs baseline: 1.3201x; 1.3201x over previous
//
#include <hip/hip_runtime.h>
#include <math.h>

#define BATCH   32
#define N_BEADS 16384
#define BEAD_SIZE 16
#define N_ATOMS 100000
#define INV_SQRT2 0.70710678118654752440f
#define SCAN_BLK 256

// ======================= build chain =======================
// countrec: histogram + rec1[m] = {slot(bits), w0, w1, w2} (m-order, for rot & fill)
__global__ void __launch_bounds__(256)
countrec_kernel(const int* __restrict__ atom_idx,
                const int* __restrict__ slot_idx,
                const float* __restrict__ W,
                int* __restrict__ counts,
                float4* __restrict__ rec1,
                int M)
{
    int m = blockIdx.x * blockDim.x + threadIdx.x;
    if (m >= M) return;
    atomicAdd(&counts[atom_idx[m]], 1);
    int slot = slot_idx[m];
    int h = slot >> 4, l = slot & 15;
    float w0 = W[(0 * N_BEADS + h) * BEAD_SIZE + l];
    float w1 = W[(1 * N_BEADS + h) * BEAD_SIZE + l];
    float w2 = W[(2 * N_BEADS + h) * BEAD_SIZE + l];
    rec1[m] = make_float4(__int_as_float(slot), w0, w1, w2);
}

// per-block exclusive scan; block sums out
__global__ void __launch_bounds__(SCAN_BLK)
scan1_kernel(const int* __restrict__ counts, int* __restrict__ off,
             int* __restrict__ bsum, int n)
{
    __shared__ int s[SCAN_BLK];
    int i = blockIdx.x * SCAN_BLK + threadIdx.x;
    int c = (i < n) ? counts[i] : 0;
    s[threadIdx.x] = c;
    __syncthreads();
    int v = c;
    for (int d = 1; d < SCAN_BLK; d <<= 1) {
        int t = (threadIdx.x >= d) ? s[threadIdx.x - d] : 0;
        __syncthreads();
        v += t;
        s[threadIdx.x] = v;
        __syncthreads();
    }
    if (i < n) off[i] = v - c;
    if (threadIdx.x == SCAN_BLK - 1) bsum[blockIdx.x] = v;
}

// finalize offsets (each block reduces its own bsum prefix), zero cursor,
// build per-atom record {cnt, off, scal}
__global__ void __launch_bounds__(256)
scan3_kernel(int* __restrict__ off, const int* __restrict__ bsum,
             const int* __restrict__ counts, const float* __restrict__ scal,
             int* __restrict__ cursor2, float4* __restrict__ rec_a, int n)
{
    __shared__ int red[256];
    int j = blockIdx.x;
    int partial = 0;
    for (int i = threadIdx.x; i < j; i += 256) partial += bsum[i];
    red[threadIdx.x] = partial;
    __syncthreads();
    for (int d = 128; d > 0; d >>= 1) {
        if ((int)threadIdx.x < d) red[threadIdx.x] += red[threadIdx.x + d];
        __syncthreads();
    }
    int bpref = red[0];

    int i = j * 256 + threadIdx.x;
    if (i >= n) return;
    int o = off[i] + bpref;
    off[i] = o;
    cursor2[i] = 0;
    rec_a[i] = make_float4(__int_as_float(counts[i]), __int_as_float(o),
                           scal[i], 0.f);
}

// fill: scatter per-m records into CSR order (the ONE random scatter).
// recA_csr[pos] = {slot, w0, w1, w2}; recB_csr[pos] = {2*cos*sin, 2*sin^2}
__global__ void __launch_bounds__(256)
fill_kernel(const int* __restrict__ atom_idx, const int* __restrict__ off,
            const float4* __restrict__ rec1, const float* __restrict__ ang,
            int* __restrict__ cursor2,
            float4* __restrict__ recA, float2* __restrict__ recB, int M)
{
    int m = blockIdx.x * blockDim.x + threadIdx.x;
    if (m >= M) return;
    int a = atom_idx[m];
    int k = atomicAdd(&cursor2[a], 1);
    int pos = off[a] + k;
    float sa, ca;
    __sincosf(ang[m], &sa, &ca);
    recA[pos] = rec1[m];
    recB[pos] = make_float2(2.f * ca * sa, 2.f * sa * sa);
}

// ======================= pass 1: rot only =======================
__global__ void __launch_bounds__(256)
rot_kernel(const float* __restrict__ p1, const float* __restrict__ p2,
           const float4* __restrict__ rec1, float* __restrict__ out_rot, int M)
{
    int b = blockIdx.y;
    int mbase = blockIdx.x * 256;
    int m = mbase + threadIdx.x;
    __shared__ float sbuf[768];

    float rx = 0.f, ry = 0.f, rz = 0.f;
    if (m < M) {
        float4 r = rec1[m];
        int slot = __float_as_int(r.x);
        int h = slot >> 4;
        const float* p1p = p1 + ((size_t)b * N_BEADS + h) * 3;
        const float* p2p = p2 + ((size_t)b * N_BEADS + h) * 3;
        float a1x = p1p[0], a1y = p1p[1], a1z = p1p[2];
        float a2x = p2p[0], a2y = p2p[1], a2z = p2p[2];
        float cxx = (a1y * a2z - a1z * a2y) * INV_SQRT2;
        float cyy = (a1z * a2x - a1x * a2z) * INV_SQRT2;
        float czz = (a1x * a2y - a1y * a2x) * INV_SQRT2;
        rx = r.y * a1x + r.z * a2x + r.w * cxx;
        ry = r.y * a1y + r.z * a2y + r.w * cyy;
        rz = r.y * a1z + r.z * a2z + r.w * czz;
        float inv = rsqrtf(rx * rx + ry * ry + rz * rz);
        rx *= inv; ry *= inv; rz *= inv;
    }
    sbuf[threadIdx.x * 3 + 0] = rx;
    sbuf[threadIdx.x * 3 + 1] = ry;
    sbuf[threadIdx.x * 3 + 2] = rz;
    __syncthreads();

    int nm = M - mbase; if (nm > 256) nm = 256;
    int nf = nm * 3;
    size_t base = ((size_t)b * M + mbase) * 3;
    if (((base * sizeof(float)) & 15) == 0) {
        int nf4 = nf >> 2;
        float4* dst = (float4*)(out_rot + base);
        if ((int)threadIdx.x < nf4)
            dst[threadIdx.x] = ((const float4*)sbuf)[threadIdx.x];
        int done = nf4 << 2;
        int r = nf - done;
        if ((int)threadIdx.x < r)
            out_rot[base + done + threadIdx.x] = sbuf[done + threadIdx.x];
    } else if (m < M) {
        out_rot[base + threadIdx.x * 3 + 0] = rx;
        out_rot[base + threadIdx.x * 3 + 1] = ry;
        out_rot[base + threadIdx.x * 3 + 2] = rz;
    }
}

// ======================= pass 2: CSR sum, sequential rec stream =======================
// Per contribution: 24B SEQUENTIAL rec reads; p1/p2/P gathers hit the
// 3x196KB per-b slices (L1/L2). XCD x owns b = x, x+8, x+16, x+24.
__global__ void __launch_bounds__(256)
sum_kernel(const float4* __restrict__ rec_a,
           const float4* __restrict__ recA,
           const float2* __restrict__ recB,
           const float* __restrict__ p1,
           const float* __restrict__ p2,
           const float* __restrict__ P,
           float* __restrict__ out_atoms,
           int abps)
{
    int beta = blockIdx.x;
    int xcd  = beta & 7;
    int j    = beta >> 3;
    int round = j / abps;                 // 0..3
    int ablk  = j - round * abps;
    int b = xcd + 8 * round;
    int abase = ablk * 256;
    int a = abase + threadIdx.x;

    float ax = 0.f, ay = 0.f, az = 0.f;
    if (a < N_ATOMS) {
        float4 ra = rec_a[a];
        int cnt = __float_as_int(ra.x);
        int o   = __float_as_int(ra.y);
        float s = ra.z;
        const float* p1b = p1 + (size_t)b * N_BEADS * 3;
        const float* p2b = p2 + (size_t)b * N_BEADS * 3;
        const float* Pb  = P  + (size_t)b * N_BEADS * 3;
        for (int k = 0; k < cnt; ++k) {
            int pos = o + k;
            float4 rA = recA[pos];
            float2 rB = recB[pos];
            int h = __float_as_int(rA.x) >> 4;

            const float* p1p = p1b + (size_t)h * 3;
            const float* p2p = p2b + (size_t)h * 3;
            float a1x = p1p[0], a1y = p1p[1], a1z = p1p[2];
            float a2x = p2p[0], a2y = p2p[1], a2z = p2p[2];

            float cxx = (a1y * a2z - a1z * a2y) * INV_SQRT2;
            float cyy = (a1z * a2x - a1x * a2z) * INV_SQRT2;
            float czz = (a1x * a2y - a1y * a2x) * INV_SQRT2;
            float rx = rA.y * a1x + rA.z * a2x + rA.w * cxx;
            float ry = rA.y * a1y + rA.z * a2y + rA.w * cyy;
            float rz = rA.y * a1z + rA.z * a2z + rA.w * czz;
            float inv = rsqrtf(rx * rx + ry * ry + rz * rz);
            rx *= inv; ry *= inv; rz *= inv;

            // Rodrigues with v = p1 bead vector
            float ux = ry * a1z - rz * a1y;
            float uy = rz * a1x - rx * a1z;
            float uz = rx * a1y - ry * a1x;
            float wx = ry * uz - rz * uy;
            float wy = rz * ux - rx * uz;
            float wz = rx * uy - ry * ux;
            float vrx = a1x + rB.x * ux + rB.y * wx;
            float vry = a1y + rB.x * uy + rB.y * wy;
            float vrz = a1z + rB.x * uz + rB.y * wz;

            const float* Pp = Pb + (size_t)h * 3;
            ax += s * vrx + Pp[0];
            ay += s * vry + Pp[1];
            az += s * vrz + Pp[2];
        }
    }
    __shared__ float sbuf[768];
    sbuf[threadIdx.x * 3 + 0] = ax;
    sbuf[threadIdx.x * 3 + 1] = ay;
    sbuf[threadIdx.x * 3 + 2] = az;
    __syncthreads();

    int na = N_ATOMS - abase; if (na > 256) na = 256;
    int nf = na * 3;
    size_t base = ((size_t)b * N_ATOMS + abase) * 3;   // 16B-aligned
    int nf4 = nf >> 2;
    float4* dst = (float4*)(out_atoms + base);
    if ((int)threadIdx.x < nf4)
        dst[threadIdx.x] = ((const float4*)sbuf)[threadIdx.x];
    int done = nf4 << 2;
    int r = nf - done;
    if ((int)threadIdx.x < r)
        out_atoms[base + done + threadIdx.x] = sbuf[done + threadIdx.x];
}

// ======================= fallback: atomic scatter (ws-independent) =======================
__global__ void __launch_bounds__(256)
backmap_fallback(const float* __restrict__ P, const float* __restrict__ p1,
                 const float* __restrict__ p2, const float* __restrict__ W,
                 const float* __restrict__ ang, const float* __restrict__ scal,
                 const int* __restrict__ slot_idx, const int* __restrict__ atom_idx,
                 const int* __restrict__ bead_idx,
                 float* __restrict__ out_atoms, float* __restrict__ out_rot, int M)
{
    int t = blockIdx.x * blockDim.x + threadIdx.x;
    if (t >= BATCH * M) return;
    int b = t / M; int m = t - b * M;
    int slot = slot_idx[m]; int h = slot >> 4; int l = slot & 15;
    int bead = bead_idx[m]; int atom = atom_idx[m];
    const float* p1p = p1 + ((size_t)b * N_BEADS + h) * 3;
    const float* p2p = p2 + ((size_t)b * N_BEADS + h) * 3;
    float a1x = p1p[0], a1y = p1p[1], a1z = p1p[2];
    float a2x = p2p[0], a2y = p2p[1], a2z = p2p[2];
    float cx = (a1y * a2z - a1z * a2y) * INV_SQRT2;
    float cy = (a1z * a2x - a1x * a2z) * INV_SQRT2;
    float cz = (a1x * a2y - a1y * a2x) * INV_SQRT2;
    float w0 = W[(0 * N_BEADS + h) * BEAD_SIZE + l];
    float w1 = W[(1 * N_BEADS + h) * BEAD_SIZE + l];
    float w2 = W[(2 * N_BEADS + h) * BEAD_SIZE + l];
    float rx = w0 * a1x + w1 * a2x + w2 * cx;
    float ry = w0 * a1y + w1 * a2y + w2 * cy;
    float rz = w0 * a1z + w1 * a2z + w2 * cz;
    float inv = rsqrtf(rx * rx + ry * ry + rz * rz);
    rx *= inv; ry *= inv; rz *= inv;
    float* ro = out_rot + (size_t)t * 3;
    ro[0] = rx; ro[1] = ry; ro[2] = rz;
    float sa, ca; __sincosf(ang[m], &sa, &ca);
    float qw = ca, qx = sa * rx, qy = sa * ry, qz = sa * rz;
    const float* vp = p1 + ((size_t)b * N_BEADS + bead) * 3;
    float vx = vp[0], vy = vp[1], vz = vp[2];
    float tw = -qx * vx - qy * vy - qz * vz;
    float tx =  qw * vx + qy * vz - qz * vy;
    float ty =  qw * vy + qz * vx - qx * vz;
    float tz =  qw * vz + qx * vy - qy * vx;
    float vrx = -tw * qx + tx * qw - ty * qz + tz * qy;
    float vry = -tw * qy + ty * qw - tz * qx + tx * qz;
    float vrz = -tw * qz + tz * qw - tx * qy + ty * qx;
    float s = scal[atom];
    const float* Pp = P + ((size_t)b * N_BEADS + bead) * 3;
    float* op = out_atoms + ((size_t)b * N_ATOMS + atom) * 3;
    atomicAdd(op + 0, s * vrx + Pp[0]);
    atomicAdd(op + 1, s * vry + Pp[1]);
    atomicAdd(op + 2, s * vrz + Pp[2]);
}

extern "C" void kernel_launch(void* const* d_in, const int* in_sizes, int n_in,
                              void* d_out, int out_size, void* d_ws, size_t ws_size,
                              hipStream_t stream) {
    const float* P    = (const float*)d_in[0];
    const float* p1   = (const float*)d_in[1];
    const float* p2   = (const float*)d_in[2];
    const float* W    = (const float*)d_in[3];
    const float* ang  = (const float*)d_in[4];
    const float* scal = (const float*)d_in[5];
    const int* slot_idx = (const int*)d_in[6];
    const int* atom_idx = (const int*)d_in[7];
    const int* bead_idx = (const int*)d_in[8];

    int M = in_sizes[6];
    float* out_atoms = (float*)d_out;
    float* out_rot   = out_atoms + (size_t)BATCH * N_ATOMS * 3;

    int nblk = (N_ATOMS + SCAN_BLK - 1) / SCAN_BLK;   // 391

    // ws: counts|off|cursor2 (N_ATOMS ints each) | bsum (512 ints)
    //     rec1[M] f4 | recA[M] f4 | rec_a[N_ATOMS] f4 | recB[M] f2
    size_t need = (size_t)N_ATOMS * 4 * 3 + 512 * 4
                + (size_t)M * 16 * 2 + (size_t)N_ATOMS * 16 + (size_t)M * 8;

    if (ws_size >= need) {
        int* counts  = (int*)d_ws;
        int* off     = counts + N_ATOMS;
        int* cursor2 = off + N_ATOMS;
        int* bsum    = cursor2 + N_ATOMS;
        float4* rec1  = (float4*)(bsum + 512);   // prefix 1,202,048 B: 16B-aligned
        float4* recA  = rec1 + M;
        float4* rec_a = recA + M;
        float2* recB  = (float2*)(rec_a + N_ATOMS);

        hipMemsetAsync(counts, 0, (size_t)N_ATOMS * sizeof(int), stream);
        countrec_kernel<<<(M + 255) / 256, 256, 0, stream>>>(
            atom_idx, slot_idx, W, counts, rec1, M);
        scan1_kernel<<<nblk, SCAN_BLK, 0, stream>>>(counts, off, bsum, N_ATOMS);
        scan3_kernel<<<nblk, 256, 0, stream>>>(off, bsum, counts, scal,
                                               cursor2, rec_a, N_ATOMS);
        fill_kernel<<<(M + 255) / 256, 256, 0, stream>>>(
            atom_idx, off, rec1, ang, cursor2, recA, recB, M);

        dim3 g1((M + 255) / 256, BATCH);
        rot_kernel<<<g1, 256, 0, stream>>>(p1, p2, rec1, out_rot, M);

        int abps = (N_ATOMS + 255) / 256;             // 391
        sum_kernel<<<abps * BATCH, 256, 0, stream>>>(
            rec_a, recA, recB, p1, p2, P, out_atoms, abps);
        return;
    }

    // fallback: atomic scatter
    hipMemsetAsync(out_atoms, 0, (size_t)BATCH * N_ATOMS * 3 * sizeof(float), stream);
    int total = BATCH * M;
    backmap_fallback<<<(total + 255) / 256, 256, 0, stream>>>(
        P, p1, p2, W, ang, scal, slot_idx, atom_idx, bead_idx,
        out_atoms, out_rot, M);
}

// Round 7
// 124.067 us; speedup vs baseline: 1.4577x; 1.1042x over previous
//
#include <hip/hip_runtime.h>
#include <math.h>

#define BATCH   32
#define N_BEADS 16384
#define BEAD_SIZE 16
#define N_ATOMS 100000
#define INV_SQRT2 0.70710678118654752440f
#define SCAN_BLK 256
#define NB 4   // batches per thread in sum_kernel

// ======================= build chain =======================
// countrec: histogram + rec1[m] = {slot(bits), w0, w1, w2}
__global__ void __launch_bounds__(256)
countrec_kernel(const int* __restrict__ atom_idx,
                const int* __restrict__ slot_idx,
                const float* __restrict__ W,
                int* __restrict__ counts,
                float4* __restrict__ rec1,
                int M)
{
    int m = blockIdx.x * blockDim.x + threadIdx.x;
    if (m >= M) return;
    atomicAdd(&counts[atom_idx[m]], 1);
    int slot = slot_idx[m];
    int h = slot >> 4, l = slot & 15;
    float w0 = W[(0 * N_BEADS + h) * BEAD_SIZE + l];
    float w1 = W[(1 * N_BEADS + h) * BEAD_SIZE + l];
    float w2 = W[(2 * N_BEADS + h) * BEAD_SIZE + l];
    rec1[m] = make_float4(__int_as_float(slot), w0, w1, w2);
}

__global__ void __launch_bounds__(SCAN_BLK)
scan1_kernel(const int* __restrict__ counts, int* __restrict__ off,
             int* __restrict__ bsum, int n)
{
    __shared__ int s[SCAN_BLK];
    int i = blockIdx.x * SCAN_BLK + threadIdx.x;
    int c = (i < n) ? counts[i] : 0;
    s[threadIdx.x] = c;
    __syncthreads();
    int v = c;
    for (int d = 1; d < SCAN_BLK; d <<= 1) {
        int t = (threadIdx.x >= d) ? s[threadIdx.x - d] : 0;
        __syncthreads();
        v += t;
        s[threadIdx.x] = v;
        __syncthreads();
    }
    if (i < n) off[i] = v - c;
    if (threadIdx.x == SCAN_BLK - 1) bsum[blockIdx.x] = v;
}

__global__ void __launch_bounds__(256)
scan3_kernel(int* __restrict__ off, const int* __restrict__ bsum,
             const int* __restrict__ counts, const float* __restrict__ scal,
             int* __restrict__ cursor2, float4* __restrict__ rec_a, int n)
{
    __shared__ int red[256];
    int j = blockIdx.x;
    int partial = 0;
    for (int i = threadIdx.x; i < j; i += 256) partial += bsum[i];
    red[threadIdx.x] = partial;
    __syncthreads();
    for (int d = 128; d > 0; d >>= 1) {
        if ((int)threadIdx.x < d) red[threadIdx.x] += red[threadIdx.x + d];
        __syncthreads();
    }
    int bpref = red[0];

    int i = j * 256 + threadIdx.x;
    if (i >= n) return;
    int o = off[i] + bpref;
    off[i] = o;
    cursor2[i] = 0;
    rec_a[i] = make_float4(__int_as_float(counts[i]), __int_as_float(o),
                           scal[i], 0.f);
}

// fill: scatter per-m records into CSR order (the ONE random scatter).
__global__ void __launch_bounds__(256)
fill_kernel(const int* __restrict__ atom_idx, const int* __restrict__ off,
            const float4* __restrict__ rec1, const float* __restrict__ ang,
            int* __restrict__ cursor2,
            float4* __restrict__ recA, float2* __restrict__ recB, int M)
{
    int m = blockIdx.x * blockDim.x + threadIdx.x;
    if (m >= M) return;
    int a = atom_idx[m];
    int k = atomicAdd(&cursor2[a], 1);
    int pos = off[a] + k;
    float sa, ca;
    __sincosf(ang[m], &sa, &ca);
    recA[pos] = rec1[m];
    recB[pos] = make_float2(2.f * ca * sa, 2.f * sa * sa);
}

// ======================= pass 1: rot only =======================
__global__ void __launch_bounds__(256)
rot_kernel(const float* __restrict__ p1, const float* __restrict__ p2,
           const float4* __restrict__ rec1, float* __restrict__ out_rot, int M)
{
    int b = blockIdx.y;
    int mbase = blockIdx.x * 256;
    int m = mbase + threadIdx.x;
    __shared__ float sbuf[768];

    float rx = 0.f, ry = 0.f, rz = 0.f;
    if (m < M) {
        float4 r = rec1[m];
        int slot = __float_as_int(r.x);
        int h = slot >> 4;
        const float* p1p = p1 + ((size_t)b * N_BEADS + h) * 3;
        const float* p2p = p2 + ((size_t)b * N_BEADS + h) * 3;
        float a1x = p1p[0], a1y = p1p[1], a1z = p1p[2];
        float a2x = p2p[0], a2y = p2p[1], a2z = p2p[2];
        float cxx = (a1y * a2z - a1z * a2y) * INV_SQRT2;
        float cyy = (a1z * a2x - a1x * a2z) * INV_SQRT2;
        float czz = (a1x * a2y - a1y * a2x) * INV_SQRT2;
        rx = r.y * a1x + r.z * a2x + r.w * cxx;
        ry = r.y * a1y + r.z * a2y + r.w * cyy;
        rz = r.y * a1z + r.z * a2z + r.w * czz;
        float inv = rsqrtf(rx * rx + ry * ry + rz * rz);
        rx *= inv; ry *= inv; rz *= inv;
    }
    sbuf[threadIdx.x * 3 + 0] = rx;
    sbuf[threadIdx.x * 3 + 1] = ry;
    sbuf[threadIdx.x * 3 + 2] = rz;
    __syncthreads();

    int nm = M - mbase; if (nm > 256) nm = 256;
    int nf = nm * 3;
    size_t base = ((size_t)b * M + mbase) * 3;
    if (((base * sizeof(float)) & 15) == 0) {
        int nf4 = nf >> 2;
        float4* dst = (float4*)(out_rot + base);
        if ((int)threadIdx.x < nf4)
            dst[threadIdx.x] = ((const float4*)sbuf)[threadIdx.x];
        int done = nf4 << 2;
        int rr = nf - done;
        if ((int)threadIdx.x < rr)
            out_rot[base + done + threadIdx.x] = sbuf[done + threadIdx.x];
    } else if (m < M) {
        out_rot[base + threadIdx.x * 3 + 0] = rx;
        out_rot[base + threadIdx.x * 3 + 1] = ry;
        out_rot[base + threadIdx.x * 3 + 2] = rz;
    }
}

// ======================= pass 2: CSR sum, NB batches per thread =======================
// Block beta: xcd = beta&7 owns b in [NB*xcd, NB*xcd+NB) -> p1/p2/P working
// set 4 x 588KB ~ 2.4MB, L2-resident per XCD. Each k-iteration carries NB
// independent gather+Rodrigues chains (4x memory-level parallelism), and the
// sequential recA/recB stream is read once per thread instead of per (b).
__global__ void __launch_bounds__(256)
sum_kernel(const float4* __restrict__ rec_a,
           const float4* __restrict__ recA,
           const float2* __restrict__ recB,
           const float* __restrict__ p1,
           const float* __restrict__ p2,
           const float* __restrict__ P,
           float* __restrict__ out_atoms)
{
    int beta = blockIdx.x;
    int xcd  = beta & 7;
    int ablk = beta >> 3;
    int b0 = xcd * NB;
    int abase = ablk * 256;
    int a = abase + threadIdx.x;

    float ax[NB], ay[NB], az[NB];
#pragma unroll
    for (int i = 0; i < NB; ++i) { ax[i] = 0.f; ay[i] = 0.f; az[i] = 0.f; }

    if (a < N_ATOMS) {
        float4 ra = rec_a[a];
        int cnt = __float_as_int(ra.x);
        int o   = __float_as_int(ra.y);
        float s = ra.z;
        const size_t bstride = (size_t)N_BEADS * 3;
        const float* p1b = p1 + (size_t)b0 * bstride;
        const float* p2b = p2 + (size_t)b0 * bstride;
        const float* Pb  = P  + (size_t)b0 * bstride;

        for (int k = 0; k < cnt; ++k) {
            int pos = o + k;
            float4 rA = recA[pos];
            float2 rB = recB[pos];
            size_t hoff = (size_t)(__float_as_int(rA.x) >> 4) * 3;

#pragma unroll
            for (int i = 0; i < NB; ++i) {
                const float* p1p = p1b + i * bstride + hoff;
                const float* p2p = p2b + i * bstride + hoff;
                float a1x = p1p[0], a1y = p1p[1], a1z = p1p[2];
                float a2x = p2p[0], a2y = p2p[1], a2z = p2p[2];

                float cxx = (a1y * a2z - a1z * a2y) * INV_SQRT2;
                float cyy = (a1z * a2x - a1x * a2z) * INV_SQRT2;
                float czz = (a1x * a2y - a1y * a2x) * INV_SQRT2;
                float rx = rA.y * a1x + rA.z * a2x + rA.w * cxx;
                float ry = rA.y * a1y + rA.z * a2y + rA.w * cyy;
                float rz = rA.y * a1z + rA.z * a2z + rA.w * czz;
                float inv = rsqrtf(rx * rx + ry * ry + rz * rz);
                rx *= inv; ry *= inv; rz *= inv;

                float ux = ry * a1z - rz * a1y;
                float uy = rz * a1x - rx * a1z;
                float uz = rx * a1y - ry * a1x;
                float wx = ry * uz - rz * uy;
                float wy = rz * ux - rx * uz;
                float wz = rx * uy - ry * ux;
                float vrx = a1x + rB.x * ux + rB.y * wx;
                float vry = a1y + rB.x * uy + rB.y * wy;
                float vrz = a1z + rB.x * uz + rB.y * wz;

                const float* Pp = Pb + i * bstride + hoff;
                ax[i] += s * vrx + Pp[0];
                ay[i] += s * vry + Pp[1];
                az[i] += s * vrz + Pp[2];
            }
        }
    }

    __shared__ float sbuf[768];
    int na = N_ATOMS - abase; if (na > 256) na = 256;
    int nf = na * 3;
    int nf4 = nf >> 2;
    int done = nf4 << 2;
    int rem = nf - done;

#pragma unroll
    for (int i = 0; i < NB; ++i) {
        __syncthreads();
        sbuf[threadIdx.x * 3 + 0] = ax[i];
        sbuf[threadIdx.x * 3 + 1] = ay[i];
        sbuf[threadIdx.x * 3 + 2] = az[i];
        __syncthreads();
        size_t base = ((size_t)(b0 + i) * N_ATOMS + abase) * 3;  // 16B-aligned
        float4* dst = (float4*)(out_atoms + base);
        if ((int)threadIdx.x < nf4)
            dst[threadIdx.x] = ((const float4*)sbuf)[threadIdx.x];
        if ((int)threadIdx.x < rem)
            out_atoms[base + done + threadIdx.x] = sbuf[done + threadIdx.x];
    }
}

// ======================= fallback: atomic scatter (ws-independent) =======================
__global__ void __launch_bounds__(256)
backmap_fallback(const float* __restrict__ P, const float* __restrict__ p1,
                 const float* __restrict__ p2, const float* __restrict__ W,
                 const float* __restrict__ ang, const float* __restrict__ scal,
                 const int* __restrict__ slot_idx, const int* __restrict__ atom_idx,
                 const int* __restrict__ bead_idx,
                 float* __restrict__ out_atoms, float* __restrict__ out_rot, int M)
{
    int t = blockIdx.x * blockDim.x + threadIdx.x;
    if (t >= BATCH * M) return;
    int b = t / M; int m = t - b * M;
    int slot = slot_idx[m]; int h = slot >> 4; int l = slot & 15;
    int bead = bead_idx[m]; int atom = atom_idx[m];
    const float* p1p = p1 + ((size_t)b * N_BEADS + h) * 3;
    const float* p2p = p2 + ((size_t)b * N_BEADS + h) * 3;
    float a1x = p1p[0], a1y = p1p[1], a1z = p1p[2];
    float a2x = p2p[0], a2y = p2p[1], a2z = p2p[2];
    float cx = (a1y * a2z - a1z * a2y) * INV_SQRT2;
    float cy = (a1z * a2x - a1x * a2z) * INV_SQRT2;
    float cz = (a1x * a2y - a1y * a2x) * INV_SQRT2;
    float w0 = W[(0 * N_BEADS + h) * BEAD_SIZE + l];
    float w1 = W[(1 * N_BEADS + h) * BEAD_SIZE + l];
    float w2 = W[(2 * N_BEADS + h) * BEAD_SIZE + l];
    float rx = w0 * a1x + w1 * a2x + w2 * cx;
    float ry = w0 * a1y + w1 * a2y + w2 * cy;
    float rz = w0 * a1z + w1 * a2z + w2 * cz;
    float inv = rsqrtf(rx * rx + ry * ry + rz * rz);
    rx *= inv; ry *= inv; rz *= inv;
    float* ro = out_rot + (size_t)t * 3;
    ro[0] = rx; ro[1] = ry; ro[2] = rz;
    float sa, ca; __sincosf(ang[m], &sa, &ca);
    float qw = ca, qx = sa * rx, qy = sa * ry, qz = sa * rz;
    const float* vp = p1 + ((size_t)b * N_BEADS + bead) * 3;
    float vx = vp[0], vy = vp[1], vz = vp[2];
    float tw = -qx * vx - qy * vy - qz * vz;
    float tx =  qw * vx + qy * vz - qz * vy;
    float ty =  qw * vy + qz * vx - qx * vz;
    float tz =  qw * vz + qx * vy - qy * vx;
    float vrx = -tw * qx + tx * qw - ty * qz + tz * qy;
    float vry = -tw * qy + ty * qw - tz * qx + tx * qz;
    float vrz = -tw * qz + tz * qw - tx * qy + ty * qx;
    float s = scal[atom];
    const float* Pp = P + ((size_t)b * N_BEADS + bead) * 3;
    float* op = out_atoms + ((size_t)b * N_ATOMS + atom) * 3;
    atomicAdd(op + 0, s * vrx + Pp[0]);
    atomicAdd(op + 1, s * vry + Pp[1]);
    atomicAdd(op + 2, s * vrz + Pp[2]);
}

extern "C" void kernel_launch(void* const* d_in, const int* in_sizes, int n_in,
                              void* d_out, int out_size, void* d_ws, size_t ws_size,
                              hipStream_t stream) {
    const float* P    = (const float*)d_in[0];
    const float* p1   = (const float*)d_in[1];
    const float* p2   = (const float*)d_in[2];
    const float* W    = (const float*)d_in[3];
    const float* ang  = (const float*)d_in[4];
    const float* scal = (const float*)d_in[5];
    const int* slot_idx = (const int*)d_in[6];
    const int* atom_idx = (const int*)d_in[7];
    const int* bead_idx = (const int*)d_in[8];

    int M = in_sizes[6];
    float* out_atoms = (float*)d_out;
    float* out_rot   = out_atoms + (size_t)BATCH * N_ATOMS * 3;

    int nblk = (N_ATOMS + SCAN_BLK - 1) / SCAN_BLK;   // 391

    size_t need = (size_t)N_ATOMS * 4 * 3 + 512 * 4
                + (size_t)M * 16 * 2 + (size_t)N_ATOMS * 16 + (size_t)M * 8;

    if (ws_size >= need) {
        int* counts  = (int*)d_ws;
        int* off     = counts + N_ATOMS;
        int* cursor2 = off + N_ATOMS;
        int* bsum    = cursor2 + N_ATOMS;
        float4* rec1  = (float4*)(bsum + 512);   // int prefix: 16B-aligned
        float4* recA  = rec1 + M;
        float4* rec_a = recA + M;
        float2* recB  = (float2*)(rec_a + N_ATOMS);

        hipMemsetAsync(counts, 0, (size_t)N_ATOMS * sizeof(int), stream);
        countrec_kernel<<<(M + 255) / 256, 256, 0, stream>>>(
            atom_idx, slot_idx, W, counts, rec1, M);
        scan1_kernel<<<nblk, SCAN_BLK, 0, stream>>>(counts, off, bsum, N_ATOMS);
        scan3_kernel<<<nblk, 256, 0, stream>>>(off, bsum, counts, scal,
                                               cursor2, rec_a, N_ATOMS);
        fill_kernel<<<(M + 255) / 256, 256, 0, stream>>>(
            atom_idx, off, rec1, ang, cursor2, recA, recB, M);

        dim3 g1((M + 255) / 256, BATCH);
        rot_kernel<<<g1, 256, 0, stream>>>(p1, p2, rec1, out_rot, M);

        int abps = (N_ATOMS + 255) / 256;             // 391
        sum_kernel<<<abps * (BATCH / NB), 256, 0, stream>>>(
            rec_a, recA, recB, p1, p2, P, out_atoms);
        return;
    }

    // fallback: atomic scatter
    hipMemsetAsync(out_atoms, 0, (size_t)BATCH * N_ATOMS * 3 * sizeof(float), stream);
    int total = BATCH * M;
    backmap_fallback<<<(total + 255) / 256, 256, 0, stream>>>(
        P, p1, p2, W, ang, scal, slot_idx, atom_idx, bead_idx,
        out_atoms, out_rot, M);
}